// Round 10
// baseline (695.668 us; speedup 1.0000x reference)
//
#include <hip/hip_runtime.h>
#include <cstddef>
#include <cstdint>

#define USER_COUNT_C 100000
#define ITEM_COUNT_C 100000
#define DIM_C 64
#define B_C 1024
#define NPOS_C 10
#define NTOP_C 50
#define CLAMP_C 40.0f
#define EPS_C 1e-5f

#define NGROUPS 6250          // 100000/16 item groups (exact)
#define TI_T 64               // items per tile
#define NTILES_T 1563         // ceil(100000/64); last tile has 32 items
#define GX 48
#define GY 16                 // 768 blocks = 3/CU

// raw barrier: LDS-drain + barrier, NO vmcnt drain (keeps producer prefetch in flight)
#define BAR() asm volatile("s_waitcnt lgkmcnt(0)\n\ts_barrier" ::: "memory")

using bf16x8 = __attribute__((ext_vector_type(8))) short;
using f32x4  = __attribute__((ext_vector_type(4))) float;

__global__ void zero_ws_kernel(float* __restrict__ ws) {
    ws[threadIdx.x] = 0.0f;  // B_C threads (fallback path only)
}

// RNE fp32 -> bf16 bits
__device__ inline short f2bf(float x) {
    uint32_t b = __float_as_uint(x);
    uint32_t r = (b + 0x7fffu + ((b >> 16) & 1u)) >> 16;
    return (short)r;
}

__device__ inline bf16x8 cvt8(const float* __restrict__ p) {
    float4 v0 = *(const float4*)p;
    float4 v1 = *(const float4*)(p + 4);
    bf16x8 r;
    r[0] = f2bf(v0.x); r[1] = f2bf(v0.y); r[2] = f2bf(v0.z); r[3] = f2bf(v0.w);
    r[4] = f2bf(v1.x); r[5] = f2bf(v1.y); r[6] = f2bf(v1.z); r[7] = f2bf(v1.w);
    return r;
}

// item_bf16 frag-ready: group g, half h, quad q, item idx16:
// 8 bf16 at (g*1024 + h*512 + q*128 + idx16*8). Also zeroes exp_sum (blocks 0-3).
__global__ __launch_bounds__(256) void prep_items_kernel(
    const float* __restrict__ item_emb, short* __restrict__ item_bf16,
    float* __restrict__ exp_sum) {
    const int t = blockIdx.x * 256 + threadIdx.x;   // NGROUPS*128 total (exact)
    if (blockIdx.x < 4) exp_sum[blockIdx.x * 256 + threadIdx.x] = 0.0f;
    const int n16 = t & 15;
    const int q   = (t >> 4) & 3;
    const int h   = (t >> 6) & 1;
    const int g   = t >> 7;
    const int i   = g * 16 + n16;
    bf16x8 v = cvt8(item_emb + (size_t)i * DIM_C + h * 32 + q * 8);
    *(bf16x8*)(item_bf16 + (size_t)g * 1024 + h * 512 + q * 128 + n16 * 8) = v;
}

// exp_sum[b] = sum_i exp(clip(u_b . item_i, +-40)) * (1 - mask[b][i])
// Producer/consumer wave specialization. Waves 0-1 stream the 64x64 mask tile
// into double-buffered LDS (fragment-order float4 slots); their next-next-tile
// loads remain in flight across the raw barrier (no vmcnt drain). Waves 2-3
// compute: items in A, resident 64-user B-frags; masks via lane-contiguous
// ds_read_b128 from LDS.
__global__ __launch_bounds__(256, 3) void expsum_pc_kernel(
    const float* __restrict__ user_emb,
    const short* __restrict__ item_bf16,
    const int*   __restrict__ batch_user,
    const float* __restrict__ mask,
    float*       __restrict__ exp_sum)
{
    // [buf][ (s*4 + j)*64 + quad*16 + n16 ]  (s: item group in tile, j: user group)
    __shared__ float4 fr[2][1024];   // 2 x 16 KB

    const int tid  = threadIdx.x;
    const int wave = tid >> 6;
    const int lane = tid & 63;
    const int uBase = blockIdx.y * 64;
    const int T_blk = (NTILES_T - blockIdx.x + GX - 1) / GX;   // >= 32 always

    if (wave < 2) {
        // ---------------- producer ----------------
        const int plane = wave * 64 + lane;   // 0..127
        const int r     = plane >> 1;         // user row 0..63
        const int half  = plane & 1;          // item half of the tile
        const int j     = r >> 4;
        const int n16   = r & 15;
        const float* mrow = mask + (size_t)(uBase + r) * ITEM_COUNT_C;

        float4 regA[8], regB[8];
        auto issue = [&](int k, float4* reg) {
            if (k >= T_blk) return;
            const int C = (blockIdx.x + k * GX) * TI_T;
            #pragma unroll
            for (int f = 0; f < 8; ++f) {
                const int col = C + half * 32 + f * 4;
                const int cc  = col < (ITEM_COUNT_C - 4) ? col : (ITEM_COUNT_C - 4);
                reg[f] = *(const float4*)(mrow + cc);
            }
        };

        issue(0, regA);
        issue(1, regB);
        for (int k = 0; k < T_blk; ++k) {
            float4* reg = (k & 1) ? regB : regA;
            const int C = (blockIdx.x + k * GX) * TI_T;
            float4* buf = fr[k & 1];
            #pragma unroll
            for (int f = 0; f < 8; ++f) {
                const int o   = half * 32 + f * 4;
                const int col = C + o;
                float4 v = reg[f];
                if (col >= ITEM_COUNT_C) v = make_float4(1.f, 1.f, 1.f, 1.f);
                const int s = o >> 4, quad = (o >> 2) & 3;
                buf[(s * 4 + j) * 64 + quad * 16 + n16] = v;
            }
            issue(k + 2, reg);   // refill the set just written (2-tile slack)
            BAR();               // "buffer k filled"
        }
    } else {
        // ---------------- consumer ----------------
        const int n16  = lane & 15;
        const int quad = lane >> 4;
        const int cw   = wave - 2;    // s-pair {0,1} or {2,3}

        // resident B fragments (users)
        bf16x8 b0[4], b1[4];
        #pragma unroll
        for (int j = 0; j < 4; ++j) {
            const int uidx = batch_user[uBase + j * 16 + n16];
            const float* us = user_emb + (size_t)uidx * DIM_C + quad * 8;
            b0[j] = cvt8(us);
            b1[j] = cvt8(us + 32);
        }
        const short* fbase = item_bf16 + quad * 128 + n16 * 8;

        float accE[4] = {0.f, 0.f, 0.f, 0.f};

        for (int k = 0; k < T_blk; ++k) {
            const int tile = blockIdx.x + k * GX;
            // A-frags for this consumer's two item groups (issued before barrier)
            const short* fp = fbase + (size_t)(tile * 4 + cw * 2) * 1024;
            const bf16x8 a00 = *(const bf16x8*)fp;
            const bf16x8 a01 = *(const bf16x8*)(fp + 512);
            const bf16x8 a10 = *(const bf16x8*)(fp + 1024);
            const bf16x8 a11 = *(const bf16x8*)(fp + 1536);

            BAR();   // buffer k&1 filled by producers
            const float4* buf = fr[k & 1];

            f32x4 acc0[4], acc1[4];
            #pragma unroll
            for (int j = 0; j < 4; ++j) {
                acc0[j] = (f32x4){0.f, 0.f, 0.f, 0.f};
                acc0[j] = __builtin_amdgcn_mfma_f32_16x16x32_bf16(a00, b0[j], acc0[j], 0, 0, 0);
                acc0[j] = __builtin_amdgcn_mfma_f32_16x16x32_bf16(a01, b1[j], acc0[j], 0, 0, 0);
                acc1[j] = (f32x4){0.f, 0.f, 0.f, 0.f};
                acc1[j] = __builtin_amdgcn_mfma_f32_16x16x32_bf16(a10, b0[j], acc1[j], 0, 0, 0);
                acc1[j] = __builtin_amdgcn_mfma_f32_16x16x32_bf16(a11, b1[j], acc1[j], 0, 0, 0);
            }
            #pragma unroll
            for (int j = 0; j < 4; ++j) {
                const float4 m0 = buf[((cw * 2 + 0) * 4 + j) * 64 + lane];
                const float4 m1 = buf[((cw * 2 + 1) * 4 + j) * 64 + lane];
                const float* m0p = (const float*)&m0;
                const float* m1p = (const float*)&m1;
                #pragma unroll
                for (int r = 0; r < 4; ++r) {
                    const float s0 = fminf(fmaxf(acc0[j][r], -CLAMP_C), CLAMP_C);
                    accE[j] += __expf(s0) * (1.0f - m0p[r]);
                    const float s1 = fminf(fmaxf(acc1[j][r], -CLAMP_C), CLAMP_C);
                    accE[j] += __expf(s1) * (1.0f - m1p[r]);
                }
            }
        }

        #pragma unroll
        for (int j = 0; j < 4; ++j) {
            accE[j] += __shfl_xor(accE[j], 16, 64);
            accE[j] += __shfl_xor(accE[j], 32, 64);
        }
        if (quad == 0) {
            #pragma unroll
            for (int j = 0; j < 4; ++j)
                atomicAdd(&exp_sum[uBase + j * 16 + n16], accE[j]);
        }
    }
}

// Fallback (ws too small for bf16 item buffer): fp32 items from global
__global__ __launch_bounds__(256) void expsum_fallback_kernel(
    const float* __restrict__ user_emb,
    const float* __restrict__ item_emb,
    const int*   __restrict__ batch_user,
    const float* __restrict__ mask,
    float*       __restrict__ exp_sum)
{
    const int tid  = threadIdx.x;
    const int wave = tid >> 6;
    const int lane = tid & 63;
    const int n16  = lane & 15;
    const int quad = lane >> 4;
    const int rowBase = blockIdx.y * 64 + wave * 16;

    const int uidx = batch_user[rowBase + n16];
    const float* usrc = user_emb + (size_t)uidx * DIM_C + quad * 8;
    const bf16x8 a0 = cvt8(usrc);
    const bf16x8 a1 = cvt8(usrc + 32);

    float accExp[4] = {0.f, 0.f, 0.f, 0.f};

    for (int t = blockIdx.x; t < NGROUPS / 4; t += 64) {
        const int ibase = t * 64;
        bf16x8 b0[4], b1[4];
        #pragma unroll
        for (int s = 0; s < 4; ++s) {
            const int gi = ibase + s * 16 + n16;
            const float* isrc = item_emb + (size_t)gi * DIM_C + quad * 8;
            b0[s] = cvt8(isrc);
            b1[s] = cvt8(isrc + 32);
        }
        f32x4 acc[4];
        #pragma unroll
        for (int s = 0; s < 4; ++s) {
            acc[s] = (f32x4){0.f, 0.f, 0.f, 0.f};
            acc[s] = __builtin_amdgcn_mfma_f32_16x16x32_bf16(a0, b0[s], acc[s], 0, 0, 0);
            acc[s] = __builtin_amdgcn_mfma_f32_16x16x32_bf16(a1, b1[s], acc[s], 0, 0, 0);
        }
        #pragma unroll
        for (int s = 0; s < 4; ++s)
            #pragma unroll
            for (int reg = 0; reg < 4; ++reg) {
                const int row = rowBase + quad * 4 + reg;
                const float sc = fminf(fmaxf(acc[s][reg], -CLAMP_C), CLAMP_C);
                const float w = 1.0f - mask[(size_t)row * ITEM_COUNT_C + ibase + s * 16 + n16];
                accExp[reg] += __expf(sc) * w;
            }
    }
    #pragma unroll
    for (int off = 1; off < 16; off <<= 1)
        #pragma unroll
        for (int reg = 0; reg < 4; ++reg)
            accExp[reg] += __shfl_xor(accExp[reg], off, 64);
    if (n16 == 0)
        #pragma unroll
        for (int reg = 0; reg < 4; ++reg)
            atomicAdd(&exp_sum[rowBase + quad * 4 + reg], accExp[reg]);
}

// per-row: 60 sampled scores (exact fp32) + loss math -> row_loss[b]
__global__ void finalize_kernel(
    const float* __restrict__ user_emb,
    const float* __restrict__ item_emb,
    const int*   __restrict__ batch_user,
    const int*   __restrict__ pos_items,
    const int*   __restrict__ top_items,
    const float* __restrict__ exp_sum,
    const int*   __restrict__ is_final,
    float*       __restrict__ row_loss)
{
    __shared__ float ush[DIM_C];
    __shared__ float s_sh[NPOS_C + NTOP_C];
    const int b = blockIdx.x;
    const int tid = threadIdx.x;  // 64 threads
    const int uidx = batch_user[b];
    if (tid < 16)
        *(float4*)&ush[tid * 4] = *(const float4*)(user_emb + (size_t)uidx * DIM_C + tid * 4);
    __syncthreads();

    if (tid < NPOS_C + NTOP_C) {
        const int idx = (tid < NPOS_C) ? pos_items[b * NPOS_C + tid]
                                       : top_items[b * NTOP_C + (tid - NPOS_C)];
        const float* iv = item_emb + (size_t)idx * DIM_C;
        float s = 0.f;
        #pragma unroll
        for (int d4 = 0; d4 < 16; ++d4) {
            const float4 a = *(const float4*)(iv + d4 * 4);
            s += a.x * ush[d4 * 4 + 0] + a.y * ush[d4 * 4 + 1]
               + a.z * ush[d4 * 4 + 2] + a.w * ush[d4 * 4 + 3];
        }
        s_sh[tid] = fminf(fmaxf(s, -CLAMP_C), CLAMP_C);
    }
    __syncthreads();

    if (tid == 0) {
        const float E = exp_sum[b];
        float L;
        if (is_final[0] != 0) {
            float sumExpTop = 0.f, above_top = 0.f;
            for (int i = 0; i < NTOP_C / 2; ++i) {
                const float v = s_sh[NPOS_C + i];
                sumExpTop += __expf(v); above_top += v;
            }
            const float below2 = E - sumExpTop;
            float above_pos = 0.f;
            for (int i = 0; i < NPOS_C; ++i) above_pos += s_sh[i];
            float c = 0.f, below_pos = 0.f;
            for (int i = 0; i < NPOS_C; ++i) {
                c += __expf(s_sh[NPOS_C - 1 - i]);
                below_pos += __logf(fmaxf(c + below2, EPS_C));
            }
            float c2 = 0.f, below_top = 0.f;
            for (int i = 0; i < NTOP_C / 2; ++i) {
                c2 += __expf(s_sh[NPOS_C + NTOP_C / 2 - 1 - i]);
                below_top += __logf(fmaxf(c2 + below2, EPS_C));
            }
            const float pos_KD = below_pos - above_pos;
            float sumExpSub = 0.f, above_sub = 0.f;
            for (int i = 0; i < NTOP_C / 10; ++i) {
                const float v = s_sh[NPOS_C + i];
                sumExpSub += __expf(v); above_sub += v;
            }
            const float below2s = E - sumExpSub;
            float c3 = 0.f, below_sub = 0.f;
            for (int i = 0; i < NTOP_C / 10; ++i) {
                c3 += __expf(s_sh[NPOS_C + NTOP_C / 10 - 1 - i]);
                below_sub += __logf(fmaxf(c3 + below2s, EPS_C));
            }
            const float top_KD = (below_top - above_top) + (below_sub - above_sub);
            L = pos_KD + 0.5f * top_KD;
        } else {
            float sumExpTop = 0.f;
            for (int i = 0; i < NTOP_C; ++i) sumExpTop += __expf(s_sh[NPOS_C + i]);
            const float els = E - sumExpTop;
            L = 0.f;
            for (int j = 0; j < NPOS_C + NTOP_C; ++j) {
                const float a = s_sh[j];
                L += __logf(fmaxf(els + __expf(a), EPS_C)) - a;
            }
        }
        row_loss[b] = L;
    }
}

__global__ void reduce_kernel(const float* __restrict__ rl, float* __restrict__ out) {
    __shared__ float part[16];
    const int tid = threadIdx.x;  // 1024 threads = 16 waves
    float v = rl[tid];
    #pragma unroll
    for (int off = 32; off > 0; off >>= 1) v += __shfl_down(v, off, 64);
    if ((tid & 63) == 0) part[tid >> 6] = v;
    __syncthreads();
    if (tid == 0) {
        float s = 0.f;
        #pragma unroll
        for (int i = 0; i < 16; ++i) s += part[i];
        out[0] = s;
    }
}

extern "C" void kernel_launch(void* const* d_in, const int* in_sizes, int n_in,
                              void* d_out, int out_size, void* d_ws, size_t ws_size,
                              hipStream_t stream) {
    const float* user_emb   = (const float*)d_in[0];
    const float* item_emb   = (const float*)d_in[1];
    const int*   batch_user = (const int*)d_in[2];
    const int*   pos_items  = (const int*)d_in[3];
    const int*   top_items  = (const int*)d_in[4];
    const float* mask       = (const float*)d_in[5];
    const int*   is_final   = (const int*)d_in[6];
    float* out = (float*)d_out;

    float* exp_sum  = (float*)d_ws;       // [B_C]
    float* row_loss = exp_sum + B_C;      // [B_C]
    short* item_bf16 = (short*)(row_loss + B_C);
    const size_t need = 2 * B_C * sizeof(float)
                      + ((size_t)NGROUPS + 16) * 1024 * sizeof(short);

    if (ws_size >= need) {
        hipLaunchKernelGGL(prep_items_kernel, dim3(NGROUPS * 128 / 256), dim3(256),
                           0, stream, item_emb, item_bf16, exp_sum);
        hipLaunchKernelGGL(expsum_pc_kernel, dim3(GX, GY), dim3(256),
                           0, stream, user_emb, item_bf16, batch_user, mask, exp_sum);
    } else {
        hipLaunchKernelGGL(zero_ws_kernel, dim3(1), dim3(B_C), 0, stream, exp_sum);
        hipLaunchKernelGGL(expsum_fallback_kernel, dim3(64, B_C / 64), dim3(256),
                           0, stream, user_emb, item_emb, batch_user, mask, exp_sum);
    }
    hipLaunchKernelGGL(finalize_kernel, dim3(B_C), dim3(64), 0, stream,
                       user_emb, item_emb, batch_user, pos_items, top_items,
                       exp_sum, is_final, row_loss);
    hipLaunchKernelGGL(reduce_kernel, dim3(1), dim3(B_C), 0, stream, row_loss, out);
}

// Round 11
// 624.900 us; speedup vs baseline: 1.1132x; 1.1132x over previous
//
#include <hip/hip_runtime.h>
#include <cstddef>
#include <cstdint>

#define USER_COUNT_C 100000
#define ITEM_COUNT_C 100000
#define DIM_C 64
#define B_C 1024
#define NPOS_C 10
#define NTOP_C 50
#define CLAMP_C 40.0f
#define EPS_C 1e-5f

#define NGROUPS 6250          // 100000/16 item groups (exact)
#define GX 64                 // item-range blocks (pass A)
#define GY 16                 // user blocks (64 users each)
#define NF4 (B_C * ITEM_COUNT_C / 4)   // 25.6M float4s in mask
#define F4_PER_ROW (ITEM_COUNT_C / 4)  // 25000

using bf16x8 = __attribute__((ext_vector_type(8))) short;
using f32x4  = __attribute__((ext_vector_type(4))) float;

__global__ void zero_ws_kernel(float* __restrict__ ws) {
    ws[blockIdx.x * 1024 + threadIdx.x] = 0.0f;  // grid covers exp_sum+exp_neg
}

// RNE fp32 -> bf16 bits
__device__ inline short f2bf(float x) {
    uint32_t b = __float_as_uint(x);
    uint32_t r = (b + 0x7fffu + ((b >> 16) & 1u)) >> 16;
    return (short)r;
}

__device__ inline bf16x8 cvt8(const float* __restrict__ p) {
    float4 v0 = *(const float4*)p;
    float4 v1 = *(const float4*)(p + 4);
    bf16x8 r;
    r[0] = f2bf(v0.x); r[1] = f2bf(v0.y); r[2] = f2bf(v0.z); r[3] = f2bf(v0.w);
    r[4] = f2bf(v1.x); r[5] = f2bf(v1.y); r[6] = f2bf(v1.z); r[7] = f2bf(v1.w);
    return r;
}

// item_bf16 frag-ready: group g, half h, quad q, item idx16:
// 8 bf16 at (g*1024 + h*512 + q*128 + idx16*8). Also zeroes exp_sum+exp_neg.
__global__ __launch_bounds__(256) void prep_items_kernel(
    const float* __restrict__ item_emb, short* __restrict__ item_bf16,
    float* __restrict__ acc_bufs) {
    const int t = blockIdx.x * 256 + threadIdx.x;   // NGROUPS*128 total (exact)
    if (blockIdx.x < 8) acc_bufs[blockIdx.x * 256 + threadIdx.x] = 0.0f;  // 2048 floats
    const int n16 = t & 15;
    const int q   = (t >> 4) & 3;
    const int h   = (t >> 6) & 1;
    const int g   = t >> 7;
    const int i   = g * 16 + n16;
    bf16x8 v = cvt8(item_emb + (size_t)i * DIM_C + h * 32 + q * 8);
    *(bf16x8*)(item_bf16 + (size_t)g * 1024 + h * 512 + q * 128 + n16 * 8) = v;
}

// PASS A: exp_sum[b] = sum_i exp(clip(u_b . item_i, +-40))   (NO mask read)
// ITEMS in A, USERS in B (C: row=item quad*4+r, col=user n16). Wave owns 64
// users (4 resident B-frag pairs); contiguous per-wave item-group ranges.
__global__ __launch_bounds__(256, 4) void expsum_nomask_kernel(
    const float* __restrict__ user_emb,
    const short* __restrict__ item_bf16,
    const int*   __restrict__ batch_user,
    float*       __restrict__ exp_sum)
{
    const int tid  = threadIdx.x;
    const int wave = tid >> 6;
    const int lane = tid & 63;
    const int n16  = lane & 15;
    const int quad = lane >> 4;
    const int uBase = blockIdx.y * 64;

    bf16x8 b0[4], b1[4];
    #pragma unroll
    for (int j = 0; j < 4; ++j) {
        const int uidx = batch_user[uBase + j * 16 + n16];
        const float* us = user_emb + (size_t)uidx * DIM_C + quad * 8;
        b0[j] = cvt8(us);
        b1[j] = cvt8(us + 32);
    }
    const short* fbase = item_bf16 + quad * 128 + n16 * 8;

    const int bc0 = (int)(((long)blockIdx.x * NGROUPS) / GX);
    const int bc1 = (int)(((long)(blockIdx.x + 1) * NGROUPS) / GX);
    const int wc0 = bc0 + (int)(((long)(bc1 - bc0) * wave) / 4);
    const int wc1 = bc0 + (int)(((long)(bc1 - bc0) * (wave + 1)) / 4);

    float accE[4] = {0.f, 0.f, 0.f, 0.f};

    for (int c = wc0; c < wc1; ++c) {
        const short* fp = fbase + (size_t)c * 1024;
        const bf16x8 f0 = *(const bf16x8*)fp;
        const bf16x8 f1 = *(const bf16x8*)(fp + 512);
        f32x4 acc[4];
        #pragma unroll
        for (int j = 0; j < 4; ++j) {
            acc[j] = (f32x4){0.f, 0.f, 0.f, 0.f};
            acc[j] = __builtin_amdgcn_mfma_f32_16x16x32_bf16(f0, b0[j], acc[j], 0, 0, 0);
            acc[j] = __builtin_amdgcn_mfma_f32_16x16x32_bf16(f1, b1[j], acc[j], 0, 0, 0);
        }
        #pragma unroll
        for (int j = 0; j < 4; ++j)
            #pragma unroll
            for (int r = 0; r < 4; ++r) {
                const float sc = fminf(fmaxf(acc[j][r], -CLAMP_C), CLAMP_C);
                accE[j] += __expf(sc);
            }
    }

    #pragma unroll
    for (int j = 0; j < 4; ++j) {
        accE[j] += __shfl_xor(accE[j], 16, 64);
        accE[j] += __shfl_xor(accE[j], 32, 64);
    }
    if (quad == 0) {
        #pragma unroll
        for (int j = 0; j < 4; ++j)
            atomicAdd(&exp_sum[uBase + j * 16 + n16], accE[j]);
    }
}

// PASS B: exp_neg[b] = sum_i exp(clip(u_b . item_i)) * mask[b,i]
// Streamed in pure copy pattern (1KB contiguous per wave-instr, grid-stride).
// Nonzero mask entries take a slow path (exact fp32 dot); zero mask = pure read.
__global__ __launch_bounds__(256) void mask_scan_kernel(
    const float* __restrict__ mask,
    const float* __restrict__ user_emb,
    const float* __restrict__ item_emb,
    const int*   __restrict__ batch_user,
    float*       __restrict__ exp_neg)
{
    const float4* m4 = (const float4*)mask;
    const int T = gridDim.x * 256;

    auto handle = [&](float4 v, int q) {
        if (v.x != 0.f || v.y != 0.f || v.z != 0.f || v.w != 0.f) {
            const int b  = q / F4_PER_ROW;
            const int c4 = q - b * F4_PER_ROW;
            const float* u = user_emb + (size_t)batch_user[b] * DIM_C;
            const float* mp = (const float*)&v;
            #pragma unroll
            for (int k = 0; k < 4; ++k) {
                const float m = mp[k];
                if (m != 0.f) {
                    const float* iv = item_emb + (size_t)(c4 * 4 + k) * DIM_C;
                    float s = 0.f;
                    for (int d = 0; d < DIM_C; ++d) s += u[d] * iv[d];
                    s = fminf(fmaxf(s, -CLAMP_C), CLAMP_C);
                    atomicAdd(&exp_neg[b], __expf(s) * m);
                }
            }
        }
    };

    int q = blockIdx.x * 256 + threadIdx.x;
    for (; q + 3 * T < NF4; q += 4 * T) {
        const float4 v0 = m4[q];
        const float4 v1 = m4[q + T];
        const float4 v2 = m4[q + 2 * T];
        const float4 v3 = m4[q + 3 * T];
        handle(v0, q); handle(v1, q + T);
        handle(v2, q + 2 * T); handle(v3, q + 3 * T);
    }
    for (; q < NF4; q += T) handle(m4[q], q);
}

// Fallback (ws too small for bf16 item buffer): fp32 items, mask read inline
__global__ __launch_bounds__(256) void expsum_fallback_kernel(
    const float* __restrict__ user_emb,
    const float* __restrict__ item_emb,
    const int*   __restrict__ batch_user,
    const float* __restrict__ mask,
    float*       __restrict__ exp_sum)
{
    const int tid  = threadIdx.x;
    const int wave = tid >> 6;
    const int lane = tid & 63;
    const int n16  = lane & 15;
    const int quad = lane >> 4;
    const int rowBase = blockIdx.y * 64 + wave * 16;

    const int uidx = batch_user[rowBase + n16];
    const float* usrc = user_emb + (size_t)uidx * DIM_C + quad * 8;
    const bf16x8 a0 = cvt8(usrc);
    const bf16x8 a1 = cvt8(usrc + 32);

    float accExp[4] = {0.f, 0.f, 0.f, 0.f};

    for (int t = blockIdx.x; t < NGROUPS / 4; t += 64) {
        const int ibase = t * 64;
        bf16x8 b0[4], b1[4];
        #pragma unroll
        for (int s = 0; s < 4; ++s) {
            const int gi = ibase + s * 16 + n16;
            const float* isrc = item_emb + (size_t)gi * DIM_C + quad * 8;
            b0[s] = cvt8(isrc);
            b1[s] = cvt8(isrc + 32);
        }
        f32x4 acc[4];
        #pragma unroll
        for (int s = 0; s < 4; ++s) {
            acc[s] = (f32x4){0.f, 0.f, 0.f, 0.f};
            acc[s] = __builtin_amdgcn_mfma_f32_16x16x32_bf16(a0, b0[s], acc[s], 0, 0, 0);
            acc[s] = __builtin_amdgcn_mfma_f32_16x16x32_bf16(a1, b1[s], acc[s], 0, 0, 0);
        }
        #pragma unroll
        for (int s = 0; s < 4; ++s)
            #pragma unroll
            for (int reg = 0; reg < 4; ++reg) {
                const int row = rowBase + quad * 4 + reg;
                const float sc = fminf(fmaxf(acc[s][reg], -CLAMP_C), CLAMP_C);
                const float w = 1.0f - mask[(size_t)row * ITEM_COUNT_C + ibase + s * 16 + n16];
                accExp[reg] += __expf(sc) * w;
            }
    }
    #pragma unroll
    for (int off = 1; off < 16; off <<= 1)
        #pragma unroll
        for (int reg = 0; reg < 4; ++reg)
            accExp[reg] += __shfl_xor(accExp[reg], off, 64);
    if (n16 == 0)
        #pragma unroll
        for (int reg = 0; reg < 4; ++reg)
            atomicAdd(&exp_sum[rowBase + quad * 4 + reg], accExp[reg]);
}

// per-row: 60 sampled scores (exact fp32) + loss math -> row_loss[b]
__global__ void finalize_kernel(
    const float* __restrict__ user_emb,
    const float* __restrict__ item_emb,
    const int*   __restrict__ batch_user,
    const int*   __restrict__ pos_items,
    const int*   __restrict__ top_items,
    const float* __restrict__ exp_sum,
    const float* __restrict__ exp_neg,
    const int*   __restrict__ is_final,
    float*       __restrict__ row_loss)
{
    __shared__ float ush[DIM_C];
    __shared__ float s_sh[NPOS_C + NTOP_C];
    const int b = blockIdx.x;
    const int tid = threadIdx.x;  // 64 threads
    const int uidx = batch_user[b];
    if (tid < 16)
        *(float4*)&ush[tid * 4] = *(const float4*)(user_emb + (size_t)uidx * DIM_C + tid * 4);
    __syncthreads();

    if (tid < NPOS_C + NTOP_C) {
        const int idx = (tid < NPOS_C) ? pos_items[b * NPOS_C + tid]
                                       : top_items[b * NTOP_C + (tid - NPOS_C)];
        const float* iv = item_emb + (size_t)idx * DIM_C;
        float s = 0.f;
        #pragma unroll
        for (int d4 = 0; d4 < 16; ++d4) {
            const float4 a = *(const float4*)(iv + d4 * 4);
            s += a.x * ush[d4 * 4 + 0] + a.y * ush[d4 * 4 + 1]
               + a.z * ush[d4 * 4 + 2] + a.w * ush[d4 * 4 + 3];
        }
        s_sh[tid] = fminf(fmaxf(s, -CLAMP_C), CLAMP_C);
    }
    __syncthreads();

    if (tid == 0) {
        const float E = exp_sum[b] - exp_neg[b];
        float L;
        if (is_final[0] != 0) {
            float sumExpTop = 0.f, above_top = 0.f;
            for (int i = 0; i < NTOP_C / 2; ++i) {
                const float v = s_sh[NPOS_C + i];
                sumExpTop += __expf(v); above_top += v;
            }
            const float below2 = E - sumExpTop;
            float above_pos = 0.f;
            for (int i = 0; i < NPOS_C; ++i) above_pos += s_sh[i];
            float c = 0.f, below_pos = 0.f;
            for (int i = 0; i < NPOS_C; ++i) {
                c += __expf(s_sh[NPOS_C - 1 - i]);
                below_pos += __logf(fmaxf(c + below2, EPS_C));
            }
            float c2 = 0.f, below_top = 0.f;
            for (int i = 0; i < NTOP_C / 2; ++i) {
                c2 += __expf(s_sh[NPOS_C + NTOP_C / 2 - 1 - i]);
                below_top += __logf(fmaxf(c2 + below2, EPS_C));
            }
            const float pos_KD = below_pos - above_pos;
            float sumExpSub = 0.f, above_sub = 0.f;
            for (int i = 0; i < NTOP_C / 10; ++i) {
                const float v = s_sh[NPOS_C + i];
                sumExpSub += __expf(v); above_sub += v;
            }
            const float below2s = E - sumExpSub;
            float c3 = 0.f, below_sub = 0.f;
            for (int i = 0; i < NTOP_C / 10; ++i) {
                c3 += __expf(s_sh[NPOS_C + NTOP_C / 10 - 1 - i]);
                below_sub += __logf(fmaxf(c3 + below2s, EPS_C));
            }
            const float top_KD = (below_top - above_top) + (below_sub - above_sub);
            L = pos_KD + 0.5f * top_KD;
        } else {
            float sumExpTop = 0.f;
            for (int i = 0; i < NTOP_C; ++i) sumExpTop += __expf(s_sh[NPOS_C + i]);
            const float els = E - sumExpTop;
            L = 0.f;
            for (int j = 0; j < NPOS_C + NTOP_C; ++j) {
                const float a = s_sh[j];
                L += __logf(fmaxf(els + __expf(a), EPS_C)) - a;
            }
        }
        row_loss[b] = L;
    }
}

__global__ void reduce_kernel(const float* __restrict__ rl, float* __restrict__ out) {
    __shared__ float part[16];
    const int tid = threadIdx.x;  // 1024 threads = 16 waves
    float v = rl[tid];
    #pragma unroll
    for (int off = 32; off > 0; off >>= 1) v += __shfl_down(v, off, 64);
    if ((tid & 63) == 0) part[tid >> 6] = v;
    __syncthreads();
    if (tid == 0) {
        float s = 0.f;
        #pragma unroll
        for (int i = 0; i < 16; ++i) s += part[i];
        out[0] = s;
    }
}

extern "C" void kernel_launch(void* const* d_in, const int* in_sizes, int n_in,
                              void* d_out, int out_size, void* d_ws, size_t ws_size,
                              hipStream_t stream) {
    const float* user_emb   = (const float*)d_in[0];
    const float* item_emb   = (const float*)d_in[1];
    const int*   batch_user = (const int*)d_in[2];
    const int*   pos_items  = (const int*)d_in[3];
    const int*   top_items  = (const int*)d_in[4];
    const float* mask       = (const float*)d_in[5];
    const int*   is_final   = (const int*)d_in[6];
    float* out = (float*)d_out;

    float* exp_sum  = (float*)d_ws;        // [B_C]
    float* exp_neg  = exp_sum + B_C;       // [B_C]
    float* row_loss = exp_neg + B_C;       // [B_C]
    short* item_bf16 = (short*)(row_loss + B_C);
    const size_t need = 3 * B_C * sizeof(float)
                      + ((size_t)NGROUPS + 16) * 1024 * sizeof(short);

    if (ws_size >= need) {
        hipLaunchKernelGGL(prep_items_kernel, dim3(NGROUPS * 128 / 256), dim3(256),
                           0, stream, item_emb, item_bf16, exp_sum);
        hipLaunchKernelGGL(expsum_nomask_kernel, dim3(GX, GY), dim3(256),
                           0, stream, user_emb, item_bf16, batch_user, exp_sum);
        hipLaunchKernelGGL(mask_scan_kernel, dim3(2048), dim3(256),
                           0, stream, mask, user_emb, item_emb, batch_user, exp_neg);
    } else {
        hipLaunchKernelGGL(zero_ws_kernel, dim3(2), dim3(1024), 0, stream, exp_sum);
        hipLaunchKernelGGL(expsum_fallback_kernel, dim3(64, B_C / 64), dim3(256),
                           0, stream, user_emb, item_emb, batch_user, mask, exp_sum);
    }
    hipLaunchKernelGGL(finalize_kernel, dim3(B_C), dim3(64), 0, stream,
                       user_emb, item_emb, batch_user, pos_items, top_items,
                       exp_sum, exp_neg, is_final, row_loss);
    hipLaunchKernelGGL(reduce_kernel, dim3(1), dim3(B_C), 0, stream, row_loss, out);
}